// Round 5
// baseline (356.084 us; speedup 1.0000x reference)
//
#include <hip/hip_runtime.h>
#include <hip/hip_fp16.h>

// Q4_0-style dequant; harness delivers raw_data as one int32 PER BYTE.
// Block b occupies raw32[b*18 .. b*18+17]:
//   ints 0,1   : low bytes of the fp16 scale (little-endian)
//   ints 2..17 : the 16 packed quant bytes
// out[b*32 + j]      = scale * ((byte_j & 15) - 8)   j in [0,16)
// out[b*32 + 16 + j] = scale * ((byte_j >> 4) - 8)
//
// v3b: same as v3 but with native ext_vector_type for the nontemporal
// builtins (HIP_vector_type structs are rejected by the builtin).
// LDS-staged coalesced input + 2 full-line float4 stores per thread.

typedef int   nint4   __attribute__((ext_vector_type(4)));
typedef float nfloat4 __attribute__((ext_vector_type(4)));

constexpr long long NUMEL = 8192LL * 8192LL;
constexpr int QK = 32;
constexpr long long NBLOCKS = NUMEL / QK;        // 2,097,152
constexpr int BLOCK_INTS = 18;
constexpr int WG_BLOCKS = 64;                    // quant blocks per workgroup
constexpr int WG_INTS = WG_BLOCKS * BLOCK_INTS;  // 1152
constexpr int WG_INT4 = WG_INTS / 4;             // 288 staged int4

__global__ __launch_bounds__(256)
void dequant_q4_kernel(const int* __restrict__ raw32,
                       float* __restrict__ out)
{
    __shared__ int lds[WG_INTS];

    const int tid = threadIdx.x;
    const long long wg = blockIdx.x;
    const int* gsrc = raw32 + wg * WG_INTS;

    // ---- stage 4608 B, fully coalesced, nontemporal ----
    {
        nint4 v = __builtin_nontemporal_load((const nint4*)gsrc + tid);
        ((nint4*)lds)[tid] = v;                   // tid 0..255
        if (tid < WG_INT4 - 256) {                // tid 0..31 -> slots 256..287
            nint4 w = __builtin_nontemporal_load((const nint4*)gsrc + 256 + tid);
            ((nint4*)lds)[256 + tid] = w;
        }
    }
    __syncthreads();

    // ---- dequant: thread owns quant block bl = tid>>2, byte-quad jj = tid&3 ----
    const int bl = tid >> 2;                      // 0..63
    const int jj = tid & 3;                       // which 4 packed bytes
    const int base = bl * BLOCK_INTS;

    const int2 s = *(const int2*)(lds + base);    // 8 B-aligned (72*bl bytes)
    const unsigned short s16 = (unsigned short)((s.x & 0xff) | ((s.y & 0xff) << 8));
    const float scale = __half2float(__ushort_as_half(s16));

    const int2 q01 = *(const int2*)(lds + base + 2 + 4 * jj);
    const int2 q23 = *(const int2*)(lds + base + 4 + 4 * jj);

    nfloat4 lo, hi;
    lo.x = scale * (float)((q01.x & 15) - 8);
    lo.y = scale * (float)((q01.y & 15) - 8);
    lo.z = scale * (float)((q23.x & 15) - 8);
    lo.w = scale * (float)((q23.y & 15) - 8);
    hi.x = scale * (float)(((q01.x >> 4) & 15) - 8);
    hi.y = scale * (float)(((q01.y >> 4) & 15) - 8);
    hi.z = scale * (float)(((q23.x >> 4) & 15) - 8);
    hi.w = scale * (float)(((q23.y >> 4) & 15) - 8);

    // out float4 index: quant block spans 8 float4s; lo at +jj, hi at +4+jj
    nfloat4* dst = (nfloat4*)out + wg * (WG_BLOCKS * 8) + bl * 8 + jj;
    __builtin_nontemporal_store(lo, dst);
    __builtin_nontemporal_store(hi, dst + 4);
}

extern "C" void kernel_launch(void* const* d_in, const int* in_sizes, int n_in,
                              void* d_out, int out_size, void* d_ws, size_t ws_size,
                              hipStream_t stream)
{
    const int* raw32 = (const int*)d_in[0];
    float* out = (float*)d_out;

    const long long n_wg = NBLOCKS / WG_BLOCKS;   // 32,768 workgroups
    dequant_q4_kernel<<<dim3((unsigned)n_wg), dim3(256), 0, stream>>>(raw32, out);
}